// Round 6
// baseline (584.546 us; speedup 1.0000x reference)
//
#include <hip/hip_runtime.h>
#include <hip/hip_bf16.h>
#include <stdint.h>

// ---------------------------------------------------------------------------
// GIN forward, round 19: aggregation FUSED into the MLP kernel at wave
// granularity. Per 32-node strip each wave: (1) gather+sum neighbors (exact
// aggz inner loop, 16 lanes/node, 4 nodes/round x 8 rounds), write Z rows,
// s_waitcnt vmcnt(0); (2) run the proven v3 MLP body. Fabric-bound gather
// and MFMA/LDS-bound MLP now overlap across waves on each CU instead of
// running as serial kernels (61 + ~50 us/layer -> max(), not sum).
// CSR build / packing / embed unchanged from round 18.
// ---------------------------------------------------------------------------

typedef __attribute__((ext_vector_type(8))) short short8;
typedef __attribute__((ext_vector_type(16))) float float16v;
typedef __attribute__((ext_vector_type(4))) unsigned int uint4v;

#define BKT 512       // nodes per bucket (dst >> 9)
#define NBMAX 256     // max buckets held in LDS (NB = 196 here)

#define MFMA32 __builtin_amdgcn_mfma_f32_32x32x16_bf16

union U4S8 { uint4v u; short8 s; };

__device__ __forceinline__ float b2f_lo(unsigned int u) {
    return __uint_as_float(u << 16);
}
__device__ __forceinline__ float b2f_hi(unsigned int u) {
    return __uint_as_float(u & 0xffff0000u);
}
__device__ __forceinline__ unsigned short f2b(float f) {
    unsigned int u = __float_as_uint(f);
    return (unsigned short)((u + 0x7fffu + ((u >> 16) & 1u)) >> 16);  // RNE
}
__device__ __forceinline__ unsigned cvtpk_bf16(float a, float b) {
    unsigned r;
    asm("v_cvt_pk_bf16_f32 %0, %1, %2" : "=v"(r) : "v"(a), "v"(b));
    return r;  // low16 = bf16(a), high16 = bf16(b)
}
__device__ __forceinline__ void perm32swap(unsigned& a, unsigned& b) {
    asm("v_permlane32_swap_b32 %0, %1" : "+v"(a), "+v"(b));
}

__device__ __forceinline__ int edge_at(const int* ei32, int is64, long long pos) {
    if (is64) return (int)(((const long long*)ei32)[pos]);
    return ei32[pos];
}

__device__ __forceinline__ int detect_is64(const int* ei) {
    const unsigned int* eu = (const unsigned int*)ei;
    int is64 = 1;
    for (int e = 0; e < 64; ++e)
        if (eu[2 * e + 1] != 0u) { is64 = 0; break; }
    return is64;
}

// ---------------- radix partition pass 1 (detect inlined) ----------------
__global__ __launch_bounds__(256) void part_hist_kernel(
        const int* __restrict__ ei, int* __restrict__ bh, int E, int NB, int PB) {
    __shared__ int h[NBMAX];
    __shared__ int is64sh;
    const int g = blockIdx.x, tid = threadIdx.x;
    for (int i = tid; i < NB; i += 256) h[i] = 0;
    if (tid == 0) is64sh = detect_is64(ei);
    __syncthreads();
    const int is64 = is64sh;
    const int e0 = g * PB, e1 = min(e0 + PB, E);
    for (int e = e0 + tid; e < e1; e += 256) {
        int d = edge_at(ei, is64, (long long)E + e);
        atomicAdd(&h[d >> 9], 1);
    }
    __syncthreads();
    for (int i = tid; i < NB; i += 256) bh[i * gridDim.x + g] = h[i];
}

// ---------------- generic multi-block exclusive scan ----------------
__global__ __launch_bounds__(1024) void scan1_kernel(
        const int* __restrict__ in, int* __restrict__ out,
        int* __restrict__ partial, int n) {
    __shared__ int sm[1024];
    const int t = threadIdx.x;
    const int i = blockIdx.x * 1024 + t;
    int v = (i < n) ? in[i] : 0;
    sm[t] = v;
    __syncthreads();
#pragma unroll
    for (int off = 1; off < 1024; off <<= 1) {
        int x = (t >= off) ? sm[t - off] : 0;
        __syncthreads();
        sm[t] += x;
        __syncthreads();
    }
    if (i < n) out[i] = sm[t] - v;
    if (t == 1023) partial[blockIdx.x] = sm[1023];
}

__global__ __launch_bounds__(256) void scan2_kernel(
        int* __restrict__ partial, int* __restrict__ blockoff, int g1) {
    __shared__ int sm[256];
    const int t = threadIdx.x;
    int v = (t < g1) ? partial[t] : 0;
    sm[t] = v;
    __syncthreads();
#pragma unroll
    for (int off = 1; off < 256; off <<= 1) {
        int x = (t >= off) ? sm[t - off] : 0;
        __syncthreads();
        sm[t] += x;
        __syncthreads();
    }
    blockoff[t] = sm[t] - v;
}

__global__ __launch_bounds__(1024) void scan3g_kernel(
        int* __restrict__ a, const int* __restrict__ blockoff, int n) {
    int i = blockIdx.x * 1024 + threadIdx.x;
    if (i < n) a[i] += blockoff[blockIdx.x];
}

// ---------------- pass 2: scatter into bucket-contiguous staging ----------------
__global__ __launch_bounds__(256) void part_scatter_kernel(
        const int* __restrict__ ei, const int* __restrict__ bhs,
        unsigned int* __restrict__ staged, int E, int NB, int PB) {
    __shared__ int cur[NBMAX];
    __shared__ int is64sh;
    const int g = blockIdx.x, tid = threadIdx.x;
    for (int i = tid; i < NB; i += 256) cur[i] = bhs[i * gridDim.x + g];
    if (tid == 0) is64sh = detect_is64(ei);
    __syncthreads();
    const int is64 = is64sh;
    const int e0 = g * PB, e1 = min(e0 + PB, E);
    for (int e = e0 + tid; e < e1; e += 256) {
        int d = edge_at(ei, is64, (long long)E + e);
        int s = edge_at(ei, is64, (long long)e);
        int b = d >> 9;
        int p = atomicAdd(&cur[b], 1);
        staged[p] = ((unsigned int)(d & (BKT - 1)) << 17) | (unsigned int)s;
    }
}

// ---------------- pass 3: per-bucket counting sort -> offs + csr ----------------
__global__ __launch_bounds__(256) void csr_local_kernel(
        const unsigned int* __restrict__ staged, const int* __restrict__ bhs,
        int* __restrict__ offs, int* __restrict__ csr, int N, int E, int NB, int G2) {
    __shared__ int hist[BKT];
    __shared__ int cur[BKT];
    const int b = blockIdx.x;
    const int tid = threadIdx.x;
    const int start = bhs[b * G2];
    const int end = (b + 1 < NB) ? bhs[(b + 1) * G2] : E;
    const int node0 = b * BKT;
    for (int i = tid; i < BKT; i += 256) hist[i] = 0;
    __syncthreads();
    for (int i = start + tid; i < end; i += 256)
        atomicAdd(&hist[staged[i] >> 17], 1);
    __syncthreads();
    const int i0 = tid * 2, i1 = i0 + 1;
    for (int off = 1; off < BKT; off <<= 1) {
        int v0 = (i0 >= off) ? hist[i0 - off] : 0;
        int v1 = (i1 >= off) ? hist[i1 - off] : 0;
        __syncthreads();
        hist[i0] += v0;
        hist[i1] += v1;
        __syncthreads();
    }
    for (int i = tid; i < BKT; i += 256) {
        int node = node0 + i;
        if (node < N) {
            int e0 = start + ((i == 0) ? 0 : hist[i - 1]);
            offs[node] = e0;
            cur[i] = e0;
        }
    }
    if (b == NB - 1 && tid == 0) offs[N] = E;
    __syncthreads();
    for (int i = start + tid; i < end; i += 256) {
        unsigned int v = staged[i];
        int dl = v >> 17;
        int src = (int)(v & 0x1ffff);
        int p = atomicAdd(&cur[dl], 1);
        csr[p] = src;
    }
}

// ---------------- fused weight pack (32x32x16 B-fragments), 7 weights ----------------
struct PW { const float* W; unsigned short* o; int K; int KOUT; };
struct PWAll { PW d[7]; int cum[8]; };

__global__ __launch_bounds__(256) void packall_kernel(PWAll P) {
    int id = blockIdx.x * blockDim.x + threadIdx.x;
    if (id >= P.cum[7]) return;
    int w = 0;
#pragma unroll
    for (int k = 1; k < 7; ++k) w += (id >= P.cum[k]);
    const int local = id - P.cum[w];
    const float* W = P.d[w].W;
    unsigned short* out = P.d[w].o;
    const int K = P.d[w].K, KOUT = P.d[w].KOUT;
    const int KS = K / 16;
    const int l = local & 63;
    const int s = (local >> 6) % KS;
    const int T = local / (KS * 64);
    const int kbase = s * 16 + ((l >> 5) << 3);
    const int n = T * 32 + (l & 31);
#pragma unroll
    for (int j = 0; j < 8; ++j)
        out[(long long)local * 8 + j] = f2b(W[(long long)(kbase + j) * KOUT + n]);
}

// ---------------- embed: H = x(f32) @ W_embed ----------------
__global__ __launch_bounds__(256) void mm_embed(
        const float* __restrict__ X, const unsigned short* __restrict__ Wp,
        unsigned short* __restrict__ out, int Mreal) {
    constexpr int KS = 4;
    const int tid = threadIdx.x;
    const int w = tid >> 6;
    const int l = tid & 63;
    const int lm = l & 31;
    const int lk = l >> 5;
    const int wr = w & 1, wc = w >> 1;
    const long long R0 = (long long)blockIdx.x * 128 + wr * 64;
    const int T0 = (wc * 64) >> 5;

    const long long r0 = (R0 + lm < Mreal) ? (R0 + lm) : (Mreal - 1);
    const long long r1 = (R0 + 32 + lm < Mreal) ? (R0 + 32 + lm) : (Mreal - 1);
    const float* xr0 = X + r0 * 64 + lk * 8;
    const float* xr1 = X + r1 * 64 + lk * 8;
    const unsigned short* bb0 = Wp + ((long long)T0 * KS * 64 + l) * 8;
    const unsigned short* bb1 = Wp + ((long long)(T0 + 1) * KS * 64 + l) * 8;

    float16v acc00 = {}, acc01 = {}, acc10 = {}, acc11 = {};
#pragma unroll
    for (int s = 0; s < KS; ++s) {
        float4 f0a = *(const float4*)(xr0 + s * 16);
        float4 f0b = *(const float4*)(xr0 + s * 16 + 4);
        float4 f1a = *(const float4*)(xr1 + s * 16);
        float4 f1b = *(const float4*)(xr1 + s * 16 + 4);
        short8 a0, a1;
        a0[0] = (short)f2b(f0a.x); a0[1] = (short)f2b(f0a.y);
        a0[2] = (short)f2b(f0a.z); a0[3] = (short)f2b(f0a.w);
        a0[4] = (short)f2b(f0b.x); a0[5] = (short)f2b(f0b.y);
        a0[6] = (short)f2b(f0b.z); a0[7] = (short)f2b(f0b.w);
        a1[0] = (short)f2b(f1a.x); a1[1] = (short)f2b(f1a.y);
        a1[2] = (short)f2b(f1a.z); a1[3] = (short)f2b(f1a.w);
        a1[4] = (short)f2b(f1b.x); a1[5] = (short)f2b(f1b.y);
        a1[6] = (short)f2b(f1b.z); a1[7] = (short)f2b(f1b.w);
        short8 b0 = *(const short8*)(bb0 + (long long)s * 64 * 8);
        short8 b1 = *(const short8*)(bb1 + (long long)s * 64 * 8);
        acc00 = MFMA32(a0, b0, acc00, 0, 0, 0);
        acc01 = MFMA32(a0, b1, acc01, 0, 0, 0);
        acc10 = MFMA32(a1, b0, acc10, 0, 0, 0);
        acc11 = MFMA32(a1, b1, acc11, 0, 0, 0);
    }
    auto st = [&](float16v acc, long long rb, int col) {
#pragma unroll
        for (int r = 0; r < 16; ++r) {
            long long row = rb + (r & 3) + 8 * (r >> 2);
            out[row * 128 + col] = f2b(acc[r]);
        }
    };
    const long long rbase = R0 + 4 * lk;
    st(acc00, rbase,      wc * 64 + lm);
    st(acc01, rbase,      wc * 64 + 32 + lm);
    st(acc10, rbase + 32, wc * 64 + lm);
    st(acc11, rbase + 32, wc * 64 + 32 + lm);
}

// ---------------- in-register transpose macro ----------------
#define CVT_TO_PA2(ACC, P0, P1) do {                                   \
        unsigned X1 = cvtpk_bf16((ACC)[0], (ACC)[1]);                  \
        unsigned Y1 = cvtpk_bf16((ACC)[4], (ACC)[5]);                  \
        unsigned X2 = cvtpk_bf16((ACC)[2], (ACC)[3]);                  \
        unsigned Y2 = cvtpk_bf16((ACC)[6], (ACC)[7]);                  \
        perm32swap(X1, Y1); perm32swap(X2, Y2);                        \
        U4S8 u0; u0.u[0] = X1; u0.u[1] = X2; u0.u[2] = Y1; u0.u[3] = Y2; \
        (P0) = u0.s;                                                   \
        unsigned X3 = cvtpk_bf16((ACC)[8], (ACC)[9]);                  \
        unsigned Y3 = cvtpk_bf16((ACC)[12], (ACC)[13]);                \
        unsigned X4 = cvtpk_bf16((ACC)[10], (ACC)[11]);                \
        unsigned Y4 = cvtpk_bf16((ACC)[14], (ACC)[15]);                \
        perm32swap(X3, Y3); perm32swap(X4, Y4);                        \
        U4S8 u1; u1.u[0] = X3; u1.u[1] = X4; u1.u[2] = Y3; u1.u[3] = Y4; \
        (P1) = u1.s;                                                   \
    } while (0)

// ---------------- fused agg+MLP: gather phase + v3 MLP body per strip ----------------
// Per wave, per 32-node strip:
//  phase 1 (gather): 16 lanes/node, 4 nodes/round, 8 rounds; exact aggz math;
//     Z rows written to global scratch (same-wave write->read, XCD-L2 local).
//  s_waitcnt vmcnt(0) + memory clobber orders the round-trip.
//  phase 2 (MLP): v3 body — stage-1 swapped MFMA, cvt_pk+permlane transpose,
//     stage-2 interleaved, weights from LDS. No barriers after weight staging.
template<int KMID, bool RELU2, bool OUTF32>
__global__ __launch_bounds__(512, 2) void fused_aggmlp(
        const unsigned short* __restrict__ H,
        const int* __restrict__ offs, const int* __restrict__ csr,
        const float* __restrict__ epsp,
        unsigned short* __restrict__ Zb,
        const unsigned short* __restrict__ Wap, const float* __restrict__ ba,
        const unsigned short* __restrict__ Wbp, const float* __restrict__ bb,
        void* __restrict__ outp, int Mreal, int nstrips) {
    constexpr int NF = KMID / 32;
    constexpr int NCH = KMID / 16;
    constexpr int WAS = 128 * KMID;
    __shared__ unsigned short wlds[KMID * 256];
    __shared__ float blds[KMID + 128];
    const int tid = threadIdx.x;

    {
        const uint4* sa = (const uint4*)Wap;
        const uint4* sb = (const uint4*)Wbp;
        uint4* da = (uint4*)wlds;
        uint4* db = (uint4*)(wlds + WAS);
#pragma unroll
        for (int i = tid; i < KMID * 16; i += 512) { da[i] = sa[i]; db[i] = sb[i]; }
        for (int i = tid; i < KMID; i += 512) blds[i] = ba[i];
        if (tid < 128) blds[KMID + tid] = bb[tid];
    }
    __syncthreads();
    // no further barriers: waves proceed independently

    const int wid = tid >> 6;
    const int l = tid & 63;
    const int lo = l & 31;
    const int hi = l >> 5;
    const int c8 = (l & 15) << 3;
    const float e = 1.0f + epsp[0];
    const int stride = gridDim.x * 8;

    for (int strip = blockIdx.x * 8 + wid; strip < nstrips; strip += stride) {
        const long long node0 = (long long)strip * 32;

        // ---------- phase 1: gather + aggregate 32 nodes (16 lanes/node) ----------
        const unsigned short* Hc = H + c8;
#pragma unroll 1
        for (int rnd = 0; rnd < 8; ++rnd) {
            const int node = (int)node0 + rnd * 4 + (l >> 4);
            if (node < Mreal) {
                const int beg = offs[node];
                const int end = offs[node + 1];
                float a0 = 0.f, a1 = 0.f, a2 = 0.f, a3 = 0.f;
                float a4 = 0.f, a5 = 0.f, a6 = 0.f, a7 = 0.f;
                int i = beg;
                for (; i + 3 < end; i += 4) {
                    const int j0 = csr[i], j1 = csr[i + 1], j2 = csr[i + 2], j3 = csr[i + 3];
                    const uint4 u0 = *(const uint4*)(Hc + ((long long)j0 << 7));
                    const uint4 u1 = *(const uint4*)(Hc + ((long long)j1 << 7));
                    const uint4 u2 = *(const uint4*)(Hc + ((long long)j2 << 7));
                    const uint4 u3 = *(const uint4*)(Hc + ((long long)j3 << 7));
                    a0 += (b2f_lo(u0.x) + b2f_lo(u1.x)) + (b2f_lo(u2.x) + b2f_lo(u3.x));
                    a1 += (b2f_hi(u0.x) + b2f_hi(u1.x)) + (b2f_hi(u2.x) + b2f_hi(u3.x));
                    a2 += (b2f_lo(u0.y) + b2f_lo(u1.y)) + (b2f_lo(u2.y) + b2f_lo(u3.y));
                    a3 += (b2f_hi(u0.y) + b2f_hi(u1.y)) + (b2f_hi(u2.y) + b2f_hi(u3.y));
                    a4 += (b2f_lo(u0.z) + b2f_lo(u1.z)) + (b2f_lo(u2.z) + b2f_lo(u3.z));
                    a5 += (b2f_hi(u0.z) + b2f_hi(u1.z)) + (b2f_hi(u2.z) + b2f_hi(u3.z));
                    a6 += (b2f_lo(u0.w) + b2f_lo(u1.w)) + (b2f_lo(u2.w) + b2f_lo(u3.w));
                    a7 += (b2f_hi(u0.w) + b2f_hi(u1.w)) + (b2f_hi(u2.w) + b2f_hi(u3.w));
                }
                for (; i < end; ++i) {
                    const uint4 u0 = *(const uint4*)(Hc + ((long long)csr[i] << 7));
                    a0 += b2f_lo(u0.x); a1 += b2f_hi(u0.x);
                    a2 += b2f_lo(u0.y); a3 += b2f_hi(u0.y);
                    a4 += b2f_lo(u0.z); a5 += b2f_hi(u0.z);
                    a6 += b2f_lo(u0.w); a7 += b2f_hi(u0.w);
                }
                const uint4 uh = *(const uint4*)(Hc + ((long long)node << 7));
                a0 = fmaf(e, b2f_lo(uh.x), a0); a1 = fmaf(e, b2f_hi(uh.x), a1);
                a2 = fmaf(e, b2f_lo(uh.y), a2); a3 = fmaf(e, b2f_hi(uh.y), a3);
                a4 = fmaf(e, b2f_lo(uh.z), a4); a5 = fmaf(e, b2f_hi(uh.z), a5);
                a6 = fmaf(e, b2f_lo(uh.w), a6); a7 = fmaf(e, b2f_hi(uh.w), a7);
                uint4 o;
                o.x = ((unsigned int)f2b(a1) << 16) | (unsigned int)f2b(a0);
                o.y = ((unsigned int)f2b(a3) << 16) | (unsigned int)f2b(a2);
                o.z = ((unsigned int)f2b(a5) << 16) | (unsigned int)f2b(a4);
                o.w = ((unsigned int)f2b(a7) << 16) | (unsigned int)f2b(a6);
                *(uint4*)(Zb + ((long long)node << 7) + c8) = o;
            }
        }
        // order the same-wave global write -> read round-trip
        asm volatile("s_waitcnt vmcnt(0)" ::: "memory");

        // ---------- phase 2: MLP (v3 body) ----------
        long long zr = node0 + lo;
        if (zr >= Mreal) zr = Mreal - 1;
        const unsigned short* zrow = Zb + zr * 128 + hi * 8;
        short8 zc[8];
#pragma unroll
        for (int s = 0; s < 8; ++s) zc[s] = *(const short8*)(zrow + s * 16);

        float16v acc2[4] = {};

#pragma unroll
        for (int fp = 0; fp < NF / 2; ++fp) {
            const int f0 = 2 * fp, f1 = f0 + 1;
            float16v accA, accB;
#pragma unroll
            for (int q = 0; q < 4; ++q) {
                const float4 tA = *(const float4*)(blds + f0 * 32 + q * 8 + hi * 4);
                const float4 tB = *(const float4*)(blds + f1 * 32 + q * 8 + hi * 4);
                accA[4 * q + 0] = tA.x; accA[4 * q + 1] = tA.y;
                accA[4 * q + 2] = tA.z; accA[4 * q + 3] = tA.w;
                accB[4 * q + 0] = tB.x; accB[4 * q + 1] = tB.y;
                accB[4 * q + 2] = tB.z; accB[4 * q + 3] = tB.w;
            }
            const unsigned short* wa0 = wlds + ((long long)(f0 * 8) * 64 + l) * 8;
            const unsigned short* wa1 = wlds + ((long long)(f1 * 8) * 64 + l) * 8;
#pragma unroll
            for (int s = 0; s < 8; ++s) {
                short8 a0 = *(const short8*)(wa0 + s * 64 * 8);
                short8 a1 = *(const short8*)(wa1 + s * 64 * 8);
                accA = MFMA32(a0, zc[s], accA, 0, 0, 0);
                accB = MFMA32(a1, zc[s], accB, 0, 0, 0);
            }
#pragma unroll
            for (int r = 0; r < 16; ++r) {
                accA[r] = fmaxf(accA[r], 0.f);
                accB[r] = fmaxf(accB[r], 0.f);
            }
            short8 pa0, pa1, pa2, pa3;
            CVT_TO_PA2(accA, pa0, pa1);
            CVT_TO_PA2(accB, pa2, pa3);
            const unsigned short* wb = wlds + WAS + ((long long)(fp * 4) * 64 + l) * 8;
#pragma unroll
            for (int g = 0; g < 4; ++g) {
                const unsigned short* wbg = wb + (long long)g * NCH * 64 * 8;
                short8 b0 = *(const short8*)(wbg);
                short8 b1 = *(const short8*)(wbg + 64 * 8);
                short8 b2 = *(const short8*)(wbg + 2 * 64 * 8);
                short8 b3 = *(const short8*)(wbg + 3 * 64 * 8);
                acc2[g] = MFMA32(pa0, b0, acc2[g], 0, 0, 0);
                acc2[g] = MFMA32(pa1, b1, acc2[g], 0, 0, 0);
                acc2[g] = MFMA32(pa2, b2, acc2[g], 0, 0, 0);
                acc2[g] = MFMA32(pa3, b3, acc2[g], 0, 0, 0);
            }
        }

        // ---------- epilogue: bias (+ReLU) + store ----------
#pragma unroll
        for (int g = 0; g < 4; ++g) {
            const int col = g * 32 + lo;
            const float bv = blds[KMID + col];
#pragma unroll
            for (int r = 0; r < 16; ++r) {
                float v = acc2[g][r] + bv;
                if (RELU2) v = fmaxf(v, 0.f);
                const long long node = node0 + (r & 3) + 8 * (r >> 2) + 4 * hi;
                if (node < Mreal) {
                    if (OUTF32) ((float*)outp)[node * 128 + col] = v;
                    else ((unsigned short*)outp)[node * 128 + col] = f2b(v);
                }
            }
        }
    }
}

extern "C" void kernel_launch(void* const* d_in, const int* in_sizes, int n_in,
                              void* d_out, int out_size, void* d_ws, size_t ws_size,
                              hipStream_t stream) {
    const float* x    = (const float*)d_in[0];
    const int*   ei   = (const int*)d_in[1];
    const float* Wemb = (const float*)d_in[2];
    const float* eps1 = (const float*)d_in[3];
    const float* w1a  = (const float*)d_in[4];
    const float* b1a  = (const float*)d_in[5];
    const float* w1b  = (const float*)d_in[6];
    const float* b1b  = (const float*)d_in[7];
    const float* eps2 = (const float*)d_in[8];
    const float* w2a  = (const float*)d_in[9];
    const float* b2a  = (const float*)d_in[10];
    const float* w2b  = (const float*)d_in[11];
    const float* b2b  = (const float*)d_in[12];
    const float* eps3 = (const float*)d_in[13];
    const float* w3a  = (const float*)d_in[14];
    const float* b3a  = (const float*)d_in[15];
    const float* w3b  = (const float*)d_in[16];
    const float* b3b  = (const float*)d_in[17];

    const int N = in_sizes[0] / 64;   // 100000
    const int E = in_sizes[1] / 2;    // 1600000
    const int Mpad = ((N + 127) / 128) * 128;  // 100096
    const int NB = (N + BKT - 1) / BKT;   // 196
    const int G2 = 1024;
    const int PB = (E + G2 - 1) / G2;
    const int BH = NB * G2;

    char* ws = (char*)d_ws;
    size_t off = 0;
    auto alloc = [&](size_t bytes) -> void* {
        void* p = ws + off;
        off = (off + bytes + 255) & ~(size_t)255;
        return p;
    };
    unsigned short* Ha  = (unsigned short*)alloc((size_t)Mpad * 128 * 2);
    unsigned short* Hb2 = (unsigned short*)alloc((size_t)Mpad * 128 * 2);
    unsigned short* Zb  = (unsigned short*)alloc((size_t)Mpad * 128 * 2);
    unsigned short* pWe = (unsigned short*)alloc((size_t)64 * 128 * 2);
    unsigned short* p1a = (unsigned short*)alloc((size_t)128 * 128 * 2);
    unsigned short* p1b = (unsigned short*)alloc((size_t)128 * 128 * 2);
    unsigned short* p2a = (unsigned short*)alloc((size_t)128 * 256 * 2);
    unsigned short* p2b = (unsigned short*)alloc((size_t)256 * 128 * 2);
    unsigned short* p3a = (unsigned short*)alloc((size_t)128 * 256 * 2);
    unsigned short* p3b = (unsigned short*)alloc((size_t)256 * 128 * 2);
    int* offs = (int*)alloc((size_t)(N + 1) * 4);
    int* csr  = (int*)alloc((size_t)E * 4);
    unsigned int* staged = (unsigned int*)alloc((size_t)E * 4);
    int* bh   = (int*)alloc((size_t)BH * 4);
    int* bhs  = (int*)alloc((size_t)BH * 4);
    int* part = (int*)alloc(1024);
    int* boff = (int*)alloc(1024);

    // ---- CSR build (detect inlined into hist/scatter) ----
    part_hist_kernel<<<G2, 256, 0, stream>>>(ei, bh, E, NB, PB);
    const int G1 = (BH + 1023) / 1024;   // 196
    scan1_kernel<<<G1, 1024, 0, stream>>>(bh, bhs, part, BH);
    scan2_kernel<<<1, 256, 0, stream>>>(part, boff, G1);
    scan3g_kernel<<<G1, 1024, 0, stream>>>(bhs, boff, BH);
    part_scatter_kernel<<<G2, 256, 0, stream>>>(ei, bhs, staged, E, NB, PB);
    csr_local_kernel<<<NB, 256, 0, stream>>>(staged, bhs, offs, csr, N, E, NB, G2);

    // ---- fused weight packing ----
    {
        PWAll P;
        const PW descs[7] = {
            {Wemb, pWe, 64, 128}, {w1a, p1a, 128, 128}, {w1b, p1b, 128, 128},
            {w2a, p2a, 128, 256}, {w2b, p2b, 256, 128}, {w3a, p3a, 128, 256},
            {w3b, p3b, 256, 128}};
        int c = 0;
        for (int k = 0; k < 7; ++k) {
            P.d[k] = descs[k];
            P.cum[k] = c;
            c += (descs[k].KOUT / 32) * (descs[k].K / 16) * 64;
        }
        P.cum[7] = c;
        packall_kernel<<<(c + 255) / 256, 256, 0, stream>>>(P);
    }

    const int MMB = Mpad / 128;           // 782 tiles (embed)
    const int NSTRIP = (N + 31) / 32;     // 3125 strips (32 nodes each)
    const int MLPG = 256;                 // 1 block per CU (LDS-bound)

    // ---- embed: H = x @ W_embed (f32 read directly) ----
    mm_embed<<<MMB, 256, 0, stream>>>(x, pWe, Ha, N);

    // ---- layer 1: agg(Ha) -> 128 -> 128(relu) -> 128 ----
    fused_aggmlp<128, false, false><<<MLPG, 512, 0, stream>>>(
        Ha, offs, csr, eps1, Zb, p1a, b1a, p1b, b1b, Hb2, N, NSTRIP);

    // ---- layer 2: agg(Hb2) -> 128 -> 256(relu) -> 128(relu) ----
    fused_aggmlp<256, true, false><<<MLPG, 512, 0, stream>>>(
        Hb2, offs, csr, eps2, Zb, p2a, b2a, p2b, b2b, Ha, N, NSTRIP);

    // ---- layer 3: agg(Ha) -> 128 -> 256(relu) -> 128(relu), f32 out ----
    fused_aggmlp<256, true, true><<<MLPG, 512, 0, stream>>>(
        Ha, offs, csr, eps3, Zb, p3a, b3a, p3b, b3b, d_out, N, NSTRIP);
}

// Round 7
// 574.915 us; speedup vs baseline: 1.0168x; 1.0168x over previous
//
#include <hip/hip_runtime.h>
#include <hip/hip_bf16.h>
#include <stdint.h>

// ---------------------------------------------------------------------------
// GIN forward, round 20: revert to the 435-us round-15/18 structure (fusion
// experiment regressed: gather needs ~24 waves/CU, LDS-MLP caps block at 8).
// Changes vs round 18:
//  - fused_mlp6 = v3 body + GLOBAL WORK-STEALING (per-wave atomic strip grab)
//    -> removes block->CU imbalance + tail; counters zeroed in mm_embed.
//  - layer-2 MLP launched at grid 128 (others 256): if throughput-bound it
//    runs ~2x and SURFACES in the top-5 with full counters (diagnostic for
//    the unexplained ~55-us MLP floor).
// ---------------------------------------------------------------------------

typedef __attribute__((ext_vector_type(8))) short short8;
typedef __attribute__((ext_vector_type(16))) float float16v;
typedef __attribute__((ext_vector_type(4))) unsigned int uint4v;

#define BKT 512       // nodes per bucket (dst >> 9)
#define NBMAX 256     // max buckets held in LDS (NB = 196 here)

#define MFMA32 __builtin_amdgcn_mfma_f32_32x32x16_bf16

union U4S8 { uint4v u; short8 s; };

__device__ __forceinline__ float b2f_lo(unsigned int u) {
    return __uint_as_float(u << 16);
}
__device__ __forceinline__ float b2f_hi(unsigned int u) {
    return __uint_as_float(u & 0xffff0000u);
}
__device__ __forceinline__ unsigned short f2b(float f) {
    unsigned int u = __float_as_uint(f);
    return (unsigned short)((u + 0x7fffu + ((u >> 16) & 1u)) >> 16);  // RNE
}
__device__ __forceinline__ unsigned cvtpk_bf16(float a, float b) {
    unsigned r;
    asm("v_cvt_pk_bf16_f32 %0, %1, %2" : "=v"(r) : "v"(a), "v"(b));
    return r;  // low16 = bf16(a), high16 = bf16(b)
}
__device__ __forceinline__ void perm32swap(unsigned& a, unsigned& b) {
    asm("v_permlane32_swap_b32 %0, %1" : "+v"(a), "+v"(b));
}

__device__ __forceinline__ int edge_at(const int* ei32, int is64, long long pos) {
    if (is64) return (int)(((const long long*)ei32)[pos]);
    return ei32[pos];
}

__device__ __forceinline__ int detect_is64(const int* ei) {
    const unsigned int* eu = (const unsigned int*)ei;
    int is64 = 1;
    for (int e = 0; e < 64; ++e)
        if (eu[2 * e + 1] != 0u) { is64 = 0; break; }
    return is64;
}

// ---------------- radix partition pass 1 (detect inlined) ----------------
__global__ __launch_bounds__(256) void part_hist_kernel(
        const int* __restrict__ ei, int* __restrict__ bh, int E, int NB, int PB) {
    __shared__ int h[NBMAX];
    __shared__ int is64sh;
    const int g = blockIdx.x, tid = threadIdx.x;
    for (int i = tid; i < NB; i += 256) h[i] = 0;
    if (tid == 0) is64sh = detect_is64(ei);
    __syncthreads();
    const int is64 = is64sh;
    const int e0 = g * PB, e1 = min(e0 + PB, E);
    for (int e = e0 + tid; e < e1; e += 256) {
        int d = edge_at(ei, is64, (long long)E + e);
        atomicAdd(&h[d >> 9], 1);
    }
    __syncthreads();
    for (int i = tid; i < NB; i += 256) bh[i * gridDim.x + g] = h[i];
}

// ---------------- generic multi-block exclusive scan ----------------
__global__ __launch_bounds__(1024) void scan1_kernel(
        const int* __restrict__ in, int* __restrict__ out,
        int* __restrict__ partial, int n) {
    __shared__ int sm[1024];
    const int t = threadIdx.x;
    const int i = blockIdx.x * 1024 + t;
    int v = (i < n) ? in[i] : 0;
    sm[t] = v;
    __syncthreads();
#pragma unroll
    for (int off = 1; off < 1024; off <<= 1) {
        int x = (t >= off) ? sm[t - off] : 0;
        __syncthreads();
        sm[t] += x;
        __syncthreads();
    }
    if (i < n) out[i] = sm[t] - v;
    if (t == 1023) partial[blockIdx.x] = sm[1023];
}

__global__ __launch_bounds__(256) void scan2_kernel(
        int* __restrict__ partial, int* __restrict__ blockoff, int g1) {
    __shared__ int sm[256];
    const int t = threadIdx.x;
    int v = (t < g1) ? partial[t] : 0;
    sm[t] = v;
    __syncthreads();
#pragma unroll
    for (int off = 1; off < 256; off <<= 1) {
        int x = (t >= off) ? sm[t - off] : 0;
        __syncthreads();
        sm[t] += x;
        __syncthreads();
    }
    blockoff[t] = sm[t] - v;
}

__global__ __launch_bounds__(1024) void scan3g_kernel(
        int* __restrict__ a, const int* __restrict__ blockoff, int n) {
    int i = blockIdx.x * 1024 + threadIdx.x;
    if (i < n) a[i] += blockoff[blockIdx.x];
}

// ---------------- pass 2: scatter into bucket-contiguous staging ----------------
__global__ __launch_bounds__(256) void part_scatter_kernel(
        const int* __restrict__ ei, const int* __restrict__ bhs,
        unsigned int* __restrict__ staged, int E, int NB, int PB) {
    __shared__ int cur[NBMAX];
    __shared__ int is64sh;
    const int g = blockIdx.x, tid = threadIdx.x;
    for (int i = tid; i < NB; i += 256) cur[i] = bhs[i * gridDim.x + g];
    if (tid == 0) is64sh = detect_is64(ei);
    __syncthreads();
    const int is64 = is64sh;
    const int e0 = g * PB, e1 = min(e0 + PB, E);
    for (int e = e0 + tid; e < e1; e += 256) {
        int d = edge_at(ei, is64, (long long)E + e);
        int s = edge_at(ei, is64, (long long)e);
        int b = d >> 9;
        int p = atomicAdd(&cur[b], 1);
        staged[p] = ((unsigned int)(d & (BKT - 1)) << 17) | (unsigned int)s;
    }
}

// ---------------- pass 3: per-bucket counting sort -> offs + csr ----------------
__global__ __launch_bounds__(256) void csr_local_kernel(
        const unsigned int* __restrict__ staged, const int* __restrict__ bhs,
        int* __restrict__ offs, int* __restrict__ csr, int N, int E, int NB, int G2) {
    __shared__ int hist[BKT];
    __shared__ int cur[BKT];
    const int b = blockIdx.x;
    const int tid = threadIdx.x;
    const int start = bhs[b * G2];
    const int end = (b + 1 < NB) ? bhs[(b + 1) * G2] : E;
    const int node0 = b * BKT;
    for (int i = tid; i < BKT; i += 256) hist[i] = 0;
    __syncthreads();
    for (int i = start + tid; i < end; i += 256)
        atomicAdd(&hist[staged[i] >> 17], 1);
    __syncthreads();
    const int i0 = tid * 2, i1 = i0 + 1;
    for (int off = 1; off < BKT; off <<= 1) {
        int v0 = (i0 >= off) ? hist[i0 - off] : 0;
        int v1 = (i1 >= off) ? hist[i1 - off] : 0;
        __syncthreads();
        hist[i0] += v0;
        hist[i1] += v1;
        __syncthreads();
    }
    for (int i = tid; i < BKT; i += 256) {
        int node = node0 + i;
        if (node < N) {
            int e0 = start + ((i == 0) ? 0 : hist[i - 1]);
            offs[node] = e0;
            cur[i] = e0;
        }
    }
    if (b == NB - 1 && tid == 0) offs[N] = E;
    __syncthreads();
    for (int i = start + tid; i < end; i += 256) {
        unsigned int v = staged[i];
        int dl = v >> 17;
        int src = (int)(v & 0x1ffff);
        int p = atomicAdd(&cur[dl], 1);
        csr[p] = src;
    }
}

// ---------------- fused weight pack (32x32x16 B-fragments), 7 weights ----------------
struct PW { const float* W; unsigned short* o; int K; int KOUT; };
struct PWAll { PW d[7]; int cum[8]; };

__global__ __launch_bounds__(256) void packall_kernel(PWAll P) {
    int id = blockIdx.x * blockDim.x + threadIdx.x;
    if (id >= P.cum[7]) return;
    int w = 0;
#pragma unroll
    for (int k = 1; k < 7; ++k) w += (id >= P.cum[k]);
    const int local = id - P.cum[w];
    const float* W = P.d[w].W;
    unsigned short* out = P.d[w].o;
    const int K = P.d[w].K, KOUT = P.d[w].KOUT;
    const int KS = K / 16;
    const int l = local & 63;
    const int s = (local >> 6) % KS;
    const int T = local / (KS * 64);
    const int kbase = s * 16 + ((l >> 5) << 3);
    const int n = T * 32 + (l & 31);
#pragma unroll
    for (int j = 0; j < 8; ++j)
        out[(long long)local * 8 + j] = f2b(W[(long long)(kbase + j) * KOUT + n]);
}

// ---------------- embed: H = x(f32) @ W_embed (+ steal-counter reset) ----------------
__global__ __launch_bounds__(256) void mm_embed(
        const float* __restrict__ X, const unsigned short* __restrict__ Wp,
        unsigned short* __restrict__ out, int Mreal, int* __restrict__ ctrs) {
    constexpr int KS = 4;
    const int tid = threadIdx.x;
    if (blockIdx.x == 0 && tid < 3) ctrs[tid] = 0;   // reset per replay
    const int w = tid >> 6;
    const int l = tid & 63;
    const int lm = l & 31;
    const int lk = l >> 5;
    const int wr = w & 1, wc = w >> 1;
    const long long R0 = (long long)blockIdx.x * 128 + wr * 64;
    const int T0 = (wc * 64) >> 5;

    const long long r0 = (R0 + lm < Mreal) ? (R0 + lm) : (Mreal - 1);
    const long long r1 = (R0 + 32 + lm < Mreal) ? (R0 + 32 + lm) : (Mreal - 1);
    const float* xr0 = X + r0 * 64 + lk * 8;
    const float* xr1 = X + r1 * 64 + lk * 8;
    const unsigned short* bb0 = Wp + ((long long)T0 * KS * 64 + l) * 8;
    const unsigned short* bb1 = Wp + ((long long)(T0 + 1) * KS * 64 + l) * 8;

    float16v acc00 = {}, acc01 = {}, acc10 = {}, acc11 = {};
#pragma unroll
    for (int s = 0; s < KS; ++s) {
        float4 f0a = *(const float4*)(xr0 + s * 16);
        float4 f0b = *(const float4*)(xr0 + s * 16 + 4);
        float4 f1a = *(const float4*)(xr1 + s * 16);
        float4 f1b = *(const float4*)(xr1 + s * 16 + 4);
        short8 a0, a1;
        a0[0] = (short)f2b(f0a.x); a0[1] = (short)f2b(f0a.y);
        a0[2] = (short)f2b(f0a.z); a0[3] = (short)f2b(f0a.w);
        a0[4] = (short)f2b(f0b.x); a0[5] = (short)f2b(f0b.y);
        a0[6] = (short)f2b(f0b.z); a0[7] = (short)f2b(f0b.w);
        a1[0] = (short)f2b(f1a.x); a1[1] = (short)f2b(f1a.y);
        a1[2] = (short)f2b(f1a.z); a1[3] = (short)f2b(f1a.w);
        a1[4] = (short)f2b(f1b.x); a1[5] = (short)f2b(f1b.y);
        a1[6] = (short)f2b(f1b.z); a1[7] = (short)f2b(f1b.w);
        short8 b0 = *(const short8*)(bb0 + (long long)s * 64 * 8);
        short8 b1 = *(const short8*)(bb1 + (long long)s * 64 * 8);
        acc00 = MFMA32(a0, b0, acc00, 0, 0, 0);
        acc01 = MFMA32(a0, b1, acc01, 0, 0, 0);
        acc10 = MFMA32(a1, b0, acc10, 0, 0, 0);
        acc11 = MFMA32(a1, b1, acc11, 0, 0, 0);
    }
    auto st = [&](float16v acc, long long rb, int col) {
#pragma unroll
        for (int r = 0; r < 16; ++r) {
            long long row = rb + (r & 3) + 8 * (r >> 2);
            out[row * 128 + col] = f2b(acc[r]);
        }
    };
    const long long rbase = R0 + 4 * lk;
    st(acc00, rbase,      wc * 64 + lm);
    st(acc01, rbase,      wc * 64 + 32 + lm);
    st(acc10, rbase + 32, wc * 64 + lm);
    st(acc11, rbase + 32, wc * 64 + 32 + lm);
}

// ---------------- aggregation (round-15 proven version; fabric-ceiling) ----------------
__global__ __launch_bounds__(256) void aggz_kernel(
        const unsigned short* __restrict__ H, const int* __restrict__ offs,
        const int* __restrict__ csr, const float* __restrict__ eps,
        unsigned short* __restrict__ Z, int n) {
    const int node = blockIdx.x * 16 + (threadIdx.x >> 4);
    const int c8 = (threadIdx.x & 15) << 3;
    if (node >= n) return;
    const int beg = offs[node];
    const int end = offs[node + 1];
    float a0 = 0.f, a1 = 0.f, a2 = 0.f, a3 = 0.f;
    float a4 = 0.f, a5 = 0.f, a6 = 0.f, a7 = 0.f;
    int i = beg;
    for (; i + 3 < end; i += 4) {
        const int j0 = csr[i], j1 = csr[i + 1], j2 = csr[i + 2], j3 = csr[i + 3];
        const uint4 u0 = *(const uint4*)(H + ((long long)j0 << 7) + c8);
        const uint4 u1 = *(const uint4*)(H + ((long long)j1 << 7) + c8);
        const uint4 u2 = *(const uint4*)(H + ((long long)j2 << 7) + c8);
        const uint4 u3 = *(const uint4*)(H + ((long long)j3 << 7) + c8);
        a0 += (b2f_lo(u0.x) + b2f_lo(u1.x)) + (b2f_lo(u2.x) + b2f_lo(u3.x));
        a1 += (b2f_hi(u0.x) + b2f_hi(u1.x)) + (b2f_hi(u2.x) + b2f_hi(u3.x));
        a2 += (b2f_lo(u0.y) + b2f_lo(u1.y)) + (b2f_lo(u2.y) + b2f_lo(u3.y));
        a3 += (b2f_hi(u0.y) + b2f_hi(u1.y)) + (b2f_hi(u2.y) + b2f_hi(u3.y));
        a4 += (b2f_lo(u0.z) + b2f_lo(u1.z)) + (b2f_lo(u2.z) + b2f_lo(u3.z));
        a5 += (b2f_hi(u0.z) + b2f_hi(u1.z)) + (b2f_hi(u2.z) + b2f_hi(u3.z));
        a6 += (b2f_lo(u0.w) + b2f_lo(u1.w)) + (b2f_lo(u2.w) + b2f_lo(u3.w));
        a7 += (b2f_hi(u0.w) + b2f_hi(u1.w)) + (b2f_hi(u2.w) + b2f_hi(u3.w));
    }
    for (; i < end; ++i) {
        const uint4 u0 = *(const uint4*)(H + ((long long)csr[i] << 7) + c8);
        a0 += b2f_lo(u0.x); a1 += b2f_hi(u0.x);
        a2 += b2f_lo(u0.y); a3 += b2f_hi(u0.y);
        a4 += b2f_lo(u0.z); a5 += b2f_hi(u0.z);
        a6 += b2f_lo(u0.w); a7 += b2f_hi(u0.w);
    }
    const uint4 uh = *(const uint4*)(H + ((long long)node << 7) + c8);
    const float e = 1.0f + eps[0];
    a0 = fmaf(e, b2f_lo(uh.x), a0); a1 = fmaf(e, b2f_hi(uh.x), a1);
    a2 = fmaf(e, b2f_lo(uh.y), a2); a3 = fmaf(e, b2f_hi(uh.y), a3);
    a4 = fmaf(e, b2f_lo(uh.z), a4); a5 = fmaf(e, b2f_hi(uh.z), a5);
    a6 = fmaf(e, b2f_lo(uh.w), a6); a7 = fmaf(e, b2f_hi(uh.w), a7);
    uint4 o;
    o.x = ((unsigned int)f2b(a1) << 16) | (unsigned int)f2b(a0);
    o.y = ((unsigned int)f2b(a3) << 16) | (unsigned int)f2b(a2);
    o.z = ((unsigned int)f2b(a5) << 16) | (unsigned int)f2b(a4);
    o.w = ((unsigned int)f2b(a7) << 16) | (unsigned int)f2b(a6);
    *(uint4*)(Z + ((long long)node << 7) + c8) = o;
}

// ---------------- in-register transpose macro ----------------
#define CVT_TO_PA2(ACC, P0, P1) do {                                   \
        unsigned X1 = cvtpk_bf16((ACC)[0], (ACC)[1]);                  \
        unsigned Y1 = cvtpk_bf16((ACC)[4], (ACC)[5]);                  \
        unsigned X2 = cvtpk_bf16((ACC)[2], (ACC)[3]);                  \
        unsigned Y2 = cvtpk_bf16((ACC)[6], (ACC)[7]);                  \
        perm32swap(X1, Y1); perm32swap(X2, Y2);                        \
        U4S8 u0; u0.u[0] = X1; u0.u[1] = X2; u0.u[2] = Y1; u0.u[3] = Y2; \
        (P0) = u0.s;                                                   \
        unsigned X3 = cvtpk_bf16((ACC)[8], (ACC)[9]);                  \
        unsigned Y3 = cvtpk_bf16((ACC)[12], (ACC)[13]);                \
        unsigned X4 = cvtpk_bf16((ACC)[10], (ACC)[11]);                \
        unsigned Y4 = cvtpk_bf16((ACC)[14], (ACC)[15]);                \
        perm32swap(X3, Y3); perm32swap(X4, Y4);                        \
        U4S8 u1; u1.u[0] = X3; u1.u[1] = X4; u1.u[2] = Y3; u1.u[3] = Y4; \
        (P1) = u1.s;                                                   \
    } while (0)

// ---------------- fused MLP v6: v3 body + global work-stealing ----------------
template<int KMID, bool RELU2, bool OUTF32>
__global__ __launch_bounds__(512, 2) void fused_mlp6(
        const unsigned short* __restrict__ Zin,
        const unsigned short* __restrict__ Wap, const float* __restrict__ ba,
        const unsigned short* __restrict__ Wbp, const float* __restrict__ bb,
        void* __restrict__ outp, int Mreal, int nstrips, int* __restrict__ ctr) {
    constexpr int NF = KMID / 32;
    constexpr int NCH = KMID / 16;
    constexpr int WAS = 128 * KMID;
    __shared__ unsigned short wlds[KMID * 256];
    __shared__ float blds[KMID + 128];
    const int tid = threadIdx.x;

    {
        const uint4* sa = (const uint4*)Wap;
        const uint4* sb = (const uint4*)Wbp;
        uint4* da = (uint4*)wlds;
        uint4* db = (uint4*)(wlds + WAS);
#pragma unroll
        for (int i = tid; i < KMID * 16; i += 512) { da[i] = sa[i]; db[i] = sb[i]; }
        for (int i = tid; i < KMID; i += 512) blds[i] = ba[i];
        if (tid < 128) blds[KMID + tid] = bb[tid];
    }
    __syncthreads();
    // no further barriers: waves proceed independently

    const int l = tid & 63;
    const int lo = l & 31;
    const int hi = l >> 5;

    // per-wave strip steal: lane 0 grabs, broadcast to the wave
    auto steal = [&]() -> int {
        int s = 0;
        if (l == 0) s = atomicAdd(ctr, 1);
        return __shfl(s, 0);
    };

    auto zload = [&](int s_, short8* zz) {
        long long zr = (long long)s_ * 32 + lo;
        if (zr >= Mreal) zr = Mreal - 1;
        const unsigned short* zrow = Zin + zr * 128 + hi * 8;
#pragma unroll
        for (int s = 0; s < 8; ++s) zz[s] = *(const short8*)(zrow + s * 16);
    };

    int strip = steal();
    if (strip >= nstrips) return;
    short8 zc[8];
    zload(strip, zc);

    while (true) {
        const int nxt = steal();
        float16v acc2[4] = {};
        short8 zn[8];

#pragma unroll
        for (int fp = 0; fp < NF / 2; ++fp) {
            if (fp == NF / 2 - 1) {
                if (nxt < nstrips) zload(nxt, zn);
            }
            const int f0 = 2 * fp, f1 = f0 + 1;
            float16v accA, accB;
#pragma unroll
            for (int q = 0; q < 4; ++q) {
                const float4 tA = *(const float4*)(blds + f0 * 32 + q * 8 + hi * 4);
                const float4 tB = *(const float4*)(blds + f1 * 32 + q * 8 + hi * 4);
                accA[4 * q + 0] = tA.x; accA[4 * q + 1] = tA.y;
                accA[4 * q + 2] = tA.z; accA[4 * q + 3] = tA.w;
                accB[4 * q + 0] = tB.x; accB[4 * q + 1] = tB.y;
                accB[4 * q + 2] = tB.z; accB[4 * q + 3] = tB.w;
            }
            const unsigned short* wa0 = wlds + ((long long)(f0 * 8) * 64 + l) * 8;
            const unsigned short* wa1 = wlds + ((long long)(f1 * 8) * 64 + l) * 8;
#pragma unroll
            for (int s = 0; s < 8; ++s) {
                short8 a0 = *(const short8*)(wa0 + s * 64 * 8);
                short8 a1 = *(const short8*)(wa1 + s * 64 * 8);
                accA = MFMA32(a0, zc[s], accA, 0, 0, 0);
                accB = MFMA32(a1, zc[s], accB, 0, 0, 0);
            }
#pragma unroll
            for (int r = 0; r < 16; ++r) {
                accA[r] = fmaxf(accA[r], 0.f);
                accB[r] = fmaxf(accB[r], 0.f);
            }
            short8 pa0, pa1, pa2, pa3;
            CVT_TO_PA2(accA, pa0, pa1);
            CVT_TO_PA2(accB, pa2, pa3);
            const unsigned short* wb = wlds + WAS + ((long long)(fp * 4) * 64 + l) * 8;
#pragma unroll
            for (int g = 0; g < 4; ++g) {
                const unsigned short* wbg = wb + (long long)g * NCH * 64 * 8;
                short8 b0 = *(const short8*)(wbg);
                short8 b1 = *(const short8*)(wbg + 64 * 8);
                short8 b2 = *(const short8*)(wbg + 2 * 64 * 8);
                short8 b3 = *(const short8*)(wbg + 3 * 64 * 8);
                acc2[g] = MFMA32(pa0, b0, acc2[g], 0, 0, 0);
                acc2[g] = MFMA32(pa1, b1, acc2[g], 0, 0, 0);
                acc2[g] = MFMA32(pa2, b2, acc2[g], 0, 0, 0);
                acc2[g] = MFMA32(pa3, b3, acc2[g], 0, 0, 0);
            }
        }

#pragma unroll
        for (int g = 0; g < 4; ++g) {
            const int col = g * 32 + lo;
            const float bv = blds[KMID + col];
#pragma unroll
            for (int r = 0; r < 16; ++r) {
                float v = acc2[g][r] + bv;
                if (RELU2) v = fmaxf(v, 0.f);
                const long long node = (long long)strip * 32 + (r & 3) + 8 * (r >> 2) + 4 * hi;
                if (node < Mreal) {
                    if (OUTF32) ((float*)outp)[node * 128 + col] = v;
                    else ((unsigned short*)outp)[node * 128 + col] = f2b(v);
                }
            }
        }

        if (nxt >= nstrips) break;
        strip = nxt;
#pragma unroll
        for (int s = 0; s < 8; ++s) zc[s] = zn[s];
    }
}

extern "C" void kernel_launch(void* const* d_in, const int* in_sizes, int n_in,
                              void* d_out, int out_size, void* d_ws, size_t ws_size,
                              hipStream_t stream) {
    const float* x    = (const float*)d_in[0];
    const int*   ei   = (const int*)d_in[1];
    const float* Wemb = (const float*)d_in[2];
    const float* eps1 = (const float*)d_in[3];
    const float* w1a  = (const float*)d_in[4];
    const float* b1a  = (const float*)d_in[5];
    const float* w1b  = (const float*)d_in[6];
    const float* b1b  = (const float*)d_in[7];
    const float* eps2 = (const float*)d_in[8];
    const float* w2a  = (const float*)d_in[9];
    const float* b2a  = (const float*)d_in[10];
    const float* w2b  = (const float*)d_in[11];
    const float* b2b  = (const float*)d_in[12];
    const float* eps3 = (const float*)d_in[13];
    const float* w3a  = (const float*)d_in[14];
    const float* b3a  = (const float*)d_in[15];
    const float* w3b  = (const float*)d_in[16];
    const float* b3b  = (const float*)d_in[17];

    const int N = in_sizes[0] / 64;   // 100000
    const int E = in_sizes[1] / 2;    // 1600000
    const int Mpad = ((N + 127) / 128) * 128;  // 100096
    const int NB = (N + BKT - 1) / BKT;   // 196
    const int G2 = 1024;
    const int PB = (E + G2 - 1) / G2;
    const int BH = NB * G2;

    char* ws = (char*)d_ws;
    size_t off = 0;
    auto alloc = [&](size_t bytes) -> void* {
        void* p = ws + off;
        off = (off + bytes + 255) & ~(size_t)255;
        return p;
    };
    unsigned short* Ha  = (unsigned short*)alloc((size_t)Mpad * 128 * 2);
    unsigned short* Hb2 = (unsigned short*)alloc((size_t)Mpad * 128 * 2);
    unsigned short* Zb  = (unsigned short*)alloc((size_t)Mpad * 128 * 2);
    unsigned short* pWe = (unsigned short*)alloc((size_t)64 * 128 * 2);
    unsigned short* p1a = (unsigned short*)alloc((size_t)128 * 128 * 2);
    unsigned short* p1b = (unsigned short*)alloc((size_t)128 * 128 * 2);
    unsigned short* p2a = (unsigned short*)alloc((size_t)128 * 256 * 2);
    unsigned short* p2b = (unsigned short*)alloc((size_t)256 * 128 * 2);
    unsigned short* p3a = (unsigned short*)alloc((size_t)128 * 256 * 2);
    unsigned short* p3b = (unsigned short*)alloc((size_t)256 * 128 * 2);
    int* offs = (int*)alloc((size_t)(N + 1) * 4);
    int* csr  = (int*)alloc((size_t)E * 4);
    unsigned int* staged = (unsigned int*)alloc((size_t)E * 4);
    int* bh   = (int*)alloc((size_t)BH * 4);
    int* bhs  = (int*)alloc((size_t)BH * 4);
    int* part = (int*)alloc(1024);
    int* boff = (int*)alloc(1024);
    int* mctr = (int*)alloc(256);   // 3 work-steal counters

    // ---- CSR build (detect inlined into hist/scatter) ----
    part_hist_kernel<<<G2, 256, 0, stream>>>(ei, bh, E, NB, PB);
    const int G1 = (BH + 1023) / 1024;   // 196
    scan1_kernel<<<G1, 1024, 0, stream>>>(bh, bhs, part, BH);
    scan2_kernel<<<1, 256, 0, stream>>>(part, boff, G1);
    scan3g_kernel<<<G1, 1024, 0, stream>>>(bhs, boff, BH);
    part_scatter_kernel<<<G2, 256, 0, stream>>>(ei, bhs, staged, E, NB, PB);
    csr_local_kernel<<<NB, 256, 0, stream>>>(staged, bhs, offs, csr, N, E, NB, G2);

    // ---- fused weight packing ----
    {
        PWAll P;
        const PW descs[7] = {
            {Wemb, pWe, 64, 128}, {w1a, p1a, 128, 128}, {w1b, p1b, 128, 128},
            {w2a, p2a, 128, 256}, {w2b, p2b, 256, 128}, {w3a, p3a, 128, 256},
            {w3b, p3b, 256, 128}};
        int c = 0;
        for (int k = 0; k < 7; ++k) {
            P.d[k] = descs[k];
            P.cum[k] = c;
            c += (descs[k].KOUT / 32) * (descs[k].K / 16) * 64;
        }
        P.cum[7] = c;
        packall_kernel<<<(c + 255) / 256, 256, 0, stream>>>(P);
    }

    const int MMB = Mpad / 128;           // 782 tiles (embed)
    const int AGB = (N + 15) / 16;        // 16 nodes per block
    const int NSTRIP = (N + 31) / 32;     // 3125 strips (32 nodes each)

    // ---- embed: H = x @ W_embed (also resets the 3 steal counters) ----
    mm_embed<<<MMB, 256, 0, stream>>>(x, pWe, Ha, N, mctr);

    // ---- layer 1: 128 -> 128(relu) -> 128  [worksteal, grid 256] ----
    aggz_kernel<<<AGB, 256, 0, stream>>>(Ha, offs, csr, eps1, Zb, N);
    fused_mlp6<128, false, false><<<256, 512, 0, stream>>>(
        Zb, p1a, b1a, p1b, b1b, Hb2, N, NSTRIP, mctr + 0);

    // ---- layer 2: 128 -> 256(relu) -> 128(relu)  [worksteal, grid 128: DIAGNOSTIC] ----
    aggz_kernel<<<AGB, 256, 0, stream>>>(Hb2, offs, csr, eps2, Zb, N);
    fused_mlp6<256, true, false><<<128, 512, 0, stream>>>(
        Zb, p2a, b2a, p2b, b2b, Ha, N, NSTRIP, mctr + 1);

    // ---- layer 3: 128 -> 256(relu) -> 128(relu), f32 out  [worksteal, grid 256] ----
    aggz_kernel<<<AGB, 256, 0, stream>>>(Ha, offs, csr, eps3, Zb, N);
    fused_mlp6<256, true, true><<<256, 512, 0, stream>>>(
        Zb, p3a, b3a, p3b, b3b, d_out, N, NSTRIP, mctr + 2);
}

// Round 8
// 432.475 us; speedup vs baseline: 1.3516x; 1.3294x over previous
//
#include <hip/hip_runtime.h>
#include <hip/hip_bf16.h>
#include <stdint.h>

// ---------------------------------------------------------------------------
// GIN forward, round 21: round-15 v3 structure (435-us anchor) + three cuts:
//  1. MLP weight staging via global_load_lds width=16 (no VGPR round-trip;
//     staging phase was the MLP's fixed serial cost - r20 grid-A/B showed
//     the MLP is NOT throughput-bound).
//  2. scan3g kernel removed: boff folded into part_scatter / csr_local.
//  3. layer-1 MLP grid 512 (64.5 KB LDS -> 2 blocks/CU).
// Work-stealing (r20: +20 us/dispatch) and agg-fusion (r19) reverted.
// aggz untouched: 60.7 us / 3.6 TB/s / 187 MB = fabric roofline for
// random 256-B gather (fetch already below the naive 8-XCD cold-fill floor).
// ---------------------------------------------------------------------------

typedef __attribute__((ext_vector_type(8))) short short8;
typedef __attribute__((ext_vector_type(16))) float float16v;
typedef __attribute__((ext_vector_type(4))) unsigned int uint4v;

#define BKT 512       // nodes per bucket (dst >> 9)
#define NBMAX 256     // max buckets held in LDS (NB = 196 here)

#define MFMA32 __builtin_amdgcn_mfma_f32_32x32x16_bf16

union U4S8 { uint4v u; short8 s; };

__device__ __forceinline__ float b2f_lo(unsigned int u) {
    return __uint_as_float(u << 16);
}
__device__ __forceinline__ float b2f_hi(unsigned int u) {
    return __uint_as_float(u & 0xffff0000u);
}
__device__ __forceinline__ unsigned short f2b(float f) {
    unsigned int u = __float_as_uint(f);
    return (unsigned short)((u + 0x7fffu + ((u >> 16) & 1u)) >> 16);  // RNE
}
__device__ __forceinline__ unsigned cvtpk_bf16(float a, float b) {
    unsigned r;
    asm("v_cvt_pk_bf16_f32 %0, %1, %2" : "=v"(r) : "v"(a), "v"(b));
    return r;  // low16 = bf16(a), high16 = bf16(b)
}
__device__ __forceinline__ void perm32swap(unsigned& a, unsigned& b) {
    asm("v_permlane32_swap_b32 %0, %1" : "+v"(a), "+v"(b));
}

// global -> LDS direct copy, 16 B per lane. LDS dest: lane0's pointer is the
// wave-uniform base; HW lands lane l at base + l*16 (layout here is linear).
__device__ __forceinline__ void gload_lds16(const void* g, void* l) {
    __builtin_amdgcn_global_load_lds(
        (const __attribute__((address_space(1))) unsigned int*)g,
        (__attribute__((address_space(3))) unsigned int*)l, 16, 0, 0);
}

__device__ __forceinline__ int edge_at(const int* ei32, int is64, long long pos) {
    if (is64) return (int)(((const long long*)ei32)[pos]);
    return ei32[pos];
}

__device__ __forceinline__ int detect_is64(const int* ei) {
    const unsigned int* eu = (const unsigned int*)ei;
    int is64 = 1;
    for (int e = 0; e < 64; ++e)
        if (eu[2 * e + 1] != 0u) { is64 = 0; break; }
    return is64;
}

// ---------------- radix partition pass 1 (detect inlined) ----------------
__global__ __launch_bounds__(256) void part_hist_kernel(
        const int* __restrict__ ei, int* __restrict__ bh, int E, int NB, int PB) {
    __shared__ int h[NBMAX];
    __shared__ int is64sh;
    const int g = blockIdx.x, tid = threadIdx.x;
    for (int i = tid; i < NB; i += 256) h[i] = 0;
    if (tid == 0) is64sh = detect_is64(ei);
    __syncthreads();
    const int is64 = is64sh;
    const int e0 = g * PB, e1 = min(e0 + PB, E);
    for (int e = e0 + tid; e < e1; e += 256) {
        int d = edge_at(ei, is64, (long long)E + e);
        atomicAdd(&h[d >> 9], 1);
    }
    __syncthreads();
    for (int i = tid; i < NB; i += 256) bh[i * gridDim.x + g] = h[i];
}

// ---------------- scans (scan3 folded into consumers) ----------------
__global__ __launch_bounds__(1024) void scan1_kernel(
        const int* __restrict__ in, int* __restrict__ out,
        int* __restrict__ partial, int n) {
    __shared__ int sm[1024];
    const int t = threadIdx.x;
    const int i = blockIdx.x * 1024 + t;
    int v = (i < n) ? in[i] : 0;
    sm[t] = v;
    __syncthreads();
#pragma unroll
    for (int off = 1; off < 1024; off <<= 1) {
        int x = (t >= off) ? sm[t - off] : 0;
        __syncthreads();
        sm[t] += x;
        __syncthreads();
    }
    if (i < n) out[i] = sm[t] - v;
    if (t == 1023) partial[blockIdx.x] = sm[1023];
}

__global__ __launch_bounds__(256) void scan2_kernel(
        int* __restrict__ partial, int* __restrict__ blockoff, int g1) {
    __shared__ int sm[256];
    const int t = threadIdx.x;
    int v = (t < g1) ? partial[t] : 0;
    sm[t] = v;
    __syncthreads();
#pragma unroll
    for (int off = 1; off < 256; off <<= 1) {
        int x = (t >= off) ? sm[t - off] : 0;
        __syncthreads();
        sm[t] += x;
        __syncthreads();
    }
    blockoff[t] = sm[t] - v;
}

// ---------------- pass 2: scatter (boff folded: bhs[i*G+g] is in chunk i) ----------------
__global__ __launch_bounds__(256) void part_scatter_kernel(
        const int* __restrict__ ei, const int* __restrict__ bhs,
        const int* __restrict__ boff,
        unsigned int* __restrict__ staged, int E, int NB, int PB) {
    __shared__ int cur[NBMAX];
    __shared__ int is64sh;
    const int g = blockIdx.x, tid = threadIdx.x;
    for (int i = tid; i < NB; i += 256) cur[i] = bhs[i * gridDim.x + g] + boff[i];
    if (tid == 0) is64sh = detect_is64(ei);
    __syncthreads();
    const int is64 = is64sh;
    const int e0 = g * PB, e1 = min(e0 + PB, E);
    for (int e = e0 + tid; e < e1; e += 256) {
        int d = edge_at(ei, is64, (long long)E + e);
        int s = edge_at(ei, is64, (long long)e);
        int b = d >> 9;
        int p = atomicAdd(&cur[b], 1);
        staged[p] = ((unsigned int)(d & (BKT - 1)) << 17) | (unsigned int)s;
    }
}

// ---------------- pass 3: per-bucket counting sort -> offs + csr ----------------
__global__ __launch_bounds__(256) void csr_local_kernel(
        const unsigned int* __restrict__ staged, const int* __restrict__ bhs,
        const int* __restrict__ boff,
        int* __restrict__ offs, int* __restrict__ csr, int N, int E, int NB, int G2) {
    __shared__ int hist[BKT];
    __shared__ int cur[BKT];
    const int b = blockIdx.x;
    const int tid = threadIdx.x;
    const int start = bhs[b * G2] + boff[b];
    const int end = (b + 1 < NB) ? (bhs[(b + 1) * G2] + boff[b + 1]) : E;
    const int node0 = b * BKT;
    for (int i = tid; i < BKT; i += 256) hist[i] = 0;
    __syncthreads();
    for (int i = start + tid; i < end; i += 256)
        atomicAdd(&hist[staged[i] >> 17], 1);
    __syncthreads();
    const int i0 = tid * 2, i1 = i0 + 1;
    for (int off = 1; off < BKT; off <<= 1) {
        int v0 = (i0 >= off) ? hist[i0 - off] : 0;
        int v1 = (i1 >= off) ? hist[i1 - off] : 0;
        __syncthreads();
        hist[i0] += v0;
        hist[i1] += v1;
        __syncthreads();
    }
    for (int i = tid; i < BKT; i += 256) {
        int node = node0 + i;
        if (node < N) {
            int e0 = start + ((i == 0) ? 0 : hist[i - 1]);
            offs[node] = e0;
            cur[i] = e0;
        }
    }
    if (b == NB - 1 && tid == 0) offs[N] = E;
    __syncthreads();
    for (int i = start + tid; i < end; i += 256) {
        unsigned int v = staged[i];
        int dl = v >> 17;
        int src = (int)(v & 0x1ffff);
        int p = atomicAdd(&cur[dl], 1);
        csr[p] = src;
    }
}

// ---------------- fused weight pack (32x32x16 B-fragments), 7 weights ----------------
struct PW { const float* W; unsigned short* o; int K; int KOUT; };
struct PWAll { PW d[7]; int cum[8]; };

__global__ __launch_bounds__(256) void packall_kernel(PWAll P) {
    int id = blockIdx.x * blockDim.x + threadIdx.x;
    if (id >= P.cum[7]) return;
    int w = 0;
#pragma unroll
    for (int k = 1; k < 7; ++k) w += (id >= P.cum[k]);
    const int local = id - P.cum[w];
    const float* W = P.d[w].W;
    unsigned short* out = P.d[w].o;
    const int K = P.d[w].K, KOUT = P.d[w].KOUT;
    const int KS = K / 16;
    const int l = local & 63;
    const int s = (local >> 6) % KS;
    const int T = local / (KS * 64);
    const int kbase = s * 16 + ((l >> 5) << 3);
    const int n = T * 32 + (l & 31);
#pragma unroll
    for (int j = 0; j < 8; ++j)
        out[(long long)local * 8 + j] = f2b(W[(long long)(kbase + j) * KOUT + n]);
}

// ---------------- embed: H = x(f32) @ W_embed ----------------
__global__ __launch_bounds__(256) void mm_embed(
        const float* __restrict__ X, const unsigned short* __restrict__ Wp,
        unsigned short* __restrict__ out, int Mreal) {
    constexpr int KS = 4;
    const int tid = threadIdx.x;
    const int w = tid >> 6;
    const int l = tid & 63;
    const int lm = l & 31;
    const int lk = l >> 5;
    const int wr = w & 1, wc = w >> 1;
    const long long R0 = (long long)blockIdx.x * 128 + wr * 64;
    const int T0 = (wc * 64) >> 5;

    const long long r0 = (R0 + lm < Mreal) ? (R0 + lm) : (Mreal - 1);
    const long long r1 = (R0 + 32 + lm < Mreal) ? (R0 + 32 + lm) : (Mreal - 1);
    const float* xr0 = X + r0 * 64 + lk * 8;
    const float* xr1 = X + r1 * 64 + lk * 8;
    const unsigned short* bb0 = Wp + ((long long)T0 * KS * 64 + l) * 8;
    const unsigned short* bb1 = Wp + ((long long)(T0 + 1) * KS * 64 + l) * 8;

    float16v acc00 = {}, acc01 = {}, acc10 = {}, acc11 = {};
#pragma unroll
    for (int s = 0; s < KS; ++s) {
        float4 f0a = *(const float4*)(xr0 + s * 16);
        float4 f0b = *(const float4*)(xr0 + s * 16 + 4);
        float4 f1a = *(const float4*)(xr1 + s * 16);
        float4 f1b = *(const float4*)(xr1 + s * 16 + 4);
        short8 a0, a1;
        a0[0] = (short)f2b(f0a.x); a0[1] = (short)f2b(f0a.y);
        a0[2] = (short)f2b(f0a.z); a0[3] = (short)f2b(f0a.w);
        a0[4] = (short)f2b(f0b.x); a0[5] = (short)f2b(f0b.y);
        a0[6] = (short)f2b(f0b.z); a0[7] = (short)f2b(f0b.w);
        a1[0] = (short)f2b(f1a.x); a1[1] = (short)f2b(f1a.y);
        a1[2] = (short)f2b(f1a.z); a1[3] = (short)f2b(f1a.w);
        a1[4] = (short)f2b(f1b.x); a1[5] = (short)f2b(f1b.y);
        a1[6] = (short)f2b(f1b.z); a1[7] = (short)f2b(f1b.w);
        short8 b0 = *(const short8*)(bb0 + (long long)s * 64 * 8);
        short8 b1 = *(const short8*)(bb1 + (long long)s * 64 * 8);
        acc00 = MFMA32(a0, b0, acc00, 0, 0, 0);
        acc01 = MFMA32(a0, b1, acc01, 0, 0, 0);
        acc10 = MFMA32(a1, b0, acc10, 0, 0, 0);
        acc11 = MFMA32(a1, b1, acc11, 0, 0, 0);
    }
    auto st = [&](float16v acc, long long rb, int col) {
#pragma unroll
        for (int r = 0; r < 16; ++r) {
            long long row = rb + (r & 3) + 8 * (r >> 2);
            out[row * 128 + col] = f2b(acc[r]);
        }
    };
    const long long rbase = R0 + 4 * lk;
    st(acc00, rbase,      wc * 64 + lm);
    st(acc01, rbase,      wc * 64 + 32 + lm);
    st(acc10, rbase + 32, wc * 64 + lm);
    st(acc11, rbase + 32, wc * 64 + 32 + lm);
}

// ---------------- aggregation (round-15 proven version; fabric-ceiling) ----------------
__global__ __launch_bounds__(256) void aggz_kernel(
        const unsigned short* __restrict__ H, const int* __restrict__ offs,
        const int* __restrict__ csr, const float* __restrict__ eps,
        unsigned short* __restrict__ Z, int n) {
    const int node = blockIdx.x * 16 + (threadIdx.x >> 4);
    const int c8 = (threadIdx.x & 15) << 3;
    if (node >= n) return;
    const int beg = offs[node];
    const int end = offs[node + 1];
    float a0 = 0.f, a1 = 0.f, a2 = 0.f, a3 = 0.f;
    float a4 = 0.f, a5 = 0.f, a6 = 0.f, a7 = 0.f;
    int i = beg;
    for (; i + 3 < end; i += 4) {
        const int j0 = csr[i], j1 = csr[i + 1], j2 = csr[i + 2], j3 = csr[i + 3];
        const uint4 u0 = *(const uint4*)(H + ((long long)j0 << 7) + c8);
        const uint4 u1 = *(const uint4*)(H + ((long long)j1 << 7) + c8);
        const uint4 u2 = *(const uint4*)(H + ((long long)j2 << 7) + c8);
        const uint4 u3 = *(const uint4*)(H + ((long long)j3 << 7) + c8);
        a0 += (b2f_lo(u0.x) + b2f_lo(u1.x)) + (b2f_lo(u2.x) + b2f_lo(u3.x));
        a1 += (b2f_hi(u0.x) + b2f_hi(u1.x)) + (b2f_hi(u2.x) + b2f_hi(u3.x));
        a2 += (b2f_lo(u0.y) + b2f_lo(u1.y)) + (b2f_lo(u2.y) + b2f_lo(u3.y));
        a3 += (b2f_hi(u0.y) + b2f_hi(u1.y)) + (b2f_hi(u2.y) + b2f_hi(u3.y));
        a4 += (b2f_lo(u0.z) + b2f_lo(u1.z)) + (b2f_lo(u2.z) + b2f_lo(u3.z));
        a5 += (b2f_hi(u0.z) + b2f_hi(u1.z)) + (b2f_hi(u2.z) + b2f_hi(u3.z));
        a6 += (b2f_lo(u0.w) + b2f_lo(u1.w)) + (b2f_lo(u2.w) + b2f_lo(u3.w));
        a7 += (b2f_hi(u0.w) + b2f_hi(u1.w)) + (b2f_hi(u2.w) + b2f_hi(u3.w));
    }
    for (; i < end; ++i) {
        const uint4 u0 = *(const uint4*)(H + ((long long)csr[i] << 7) + c8);
        a0 += b2f_lo(u0.x); a1 += b2f_hi(u0.x);
        a2 += b2f_lo(u0.y); a3 += b2f_hi(u0.y);
        a4 += b2f_lo(u0.z); a5 += b2f_hi(u0.z);
        a6 += b2f_lo(u0.w); a7 += b2f_hi(u0.w);
    }
    const uint4 uh = *(const uint4*)(H + ((long long)node << 7) + c8);
    const float e = 1.0f + eps[0];
    a0 = fmaf(e, b2f_lo(uh.x), a0); a1 = fmaf(e, b2f_hi(uh.x), a1);
    a2 = fmaf(e, b2f_lo(uh.y), a2); a3 = fmaf(e, b2f_hi(uh.y), a3);
    a4 = fmaf(e, b2f_lo(uh.z), a4); a5 = fmaf(e, b2f_hi(uh.z), a5);
    a6 = fmaf(e, b2f_lo(uh.w), a6); a7 = fmaf(e, b2f_hi(uh.w), a7);
    uint4 o;
    o.x = ((unsigned int)f2b(a1) << 16) | (unsigned int)f2b(a0);
    o.y = ((unsigned int)f2b(a3) << 16) | (unsigned int)f2b(a2);
    o.z = ((unsigned int)f2b(a5) << 16) | (unsigned int)f2b(a4);
    o.w = ((unsigned int)f2b(a7) << 16) | (unsigned int)f2b(a6);
    *(uint4*)(Z + ((long long)node << 7) + c8) = o;
}

// ---------------- in-register transpose macro ----------------
#define CVT_TO_PA2(ACC, P0, P1) do {                                   \
        unsigned X1 = cvtpk_bf16((ACC)[0], (ACC)[1]);                  \
        unsigned Y1 = cvtpk_bf16((ACC)[4], (ACC)[5]);                  \
        unsigned X2 = cvtpk_bf16((ACC)[2], (ACC)[3]);                  \
        unsigned Y2 = cvtpk_bf16((ACC)[6], (ACC)[7]);                  \
        perm32swap(X1, Y1); perm32swap(X2, Y2);                        \
        U4S8 u0; u0.u[0] = X1; u0.u[1] = X2; u0.u[2] = Y1; u0.u[3] = Y2; \
        (P0) = u0.s;                                                   \
        unsigned X3 = cvtpk_bf16((ACC)[8], (ACC)[9]);                  \
        unsigned Y3 = cvtpk_bf16((ACC)[12], (ACC)[13]);                \
        unsigned X4 = cvtpk_bf16((ACC)[10], (ACC)[11]);                \
        unsigned Y4 = cvtpk_bf16((ACC)[14], (ACC)[15]);                \
        perm32swap(X3, Y3); perm32swap(X4, Y4);                        \
        U4S8 u1; u1.u[0] = X3; u1.u[1] = X4; u1.u[2] = Y3; u1.u[3] = Y4; \
        (P1) = u1.s;                                                   \
    } while (0)

// ---------------- fused MLP v7: v3 body + global_load_lds weight staging ----------------
template<int KMID, bool RELU2, bool OUTF32>
__global__ __launch_bounds__(512, 2) void fused_mlp7(
        const unsigned short* __restrict__ Zin,
        const unsigned short* __restrict__ Wap, const float* __restrict__ ba,
        const unsigned short* __restrict__ Wbp, const float* __restrict__ bb,
        void* __restrict__ outp, int Mreal, int nstrips) {
    constexpr int NF = KMID / 32;
    constexpr int NCH = KMID / 16;
    constexpr int WAS = 128 * KMID;     // shorts in packed Wa
    constexpr int CA = KMID * 16;       // 16B chunks in Wa (= in Wb)
    __shared__ unsigned short wlds[KMID * 256];
    __shared__ float blds[KMID + 128];
    const int tid = threadIdx.x;
    const int wid = tid >> 6;
    const int l = tid & 63;

    // ---- stage weights via direct global->LDS (no VGPR round-trip) ----
    {
        for (int c = wid * 64 + l; c < CA; c += 512) {
            gload_lds16((const uint4*)Wap + c, wlds + (size_t)c * 8);
            gload_lds16((const uint4*)Wbp + c, wlds + (size_t)(WAS + c * 8));
        }
        for (int i = tid; i < KMID; i += 512) blds[i] = ba[i];
        if (tid < 128) blds[KMID + tid] = bb[tid];
    }
    __syncthreads();   // drains vmcnt (incl. global_load_lds) + lgkmcnt
    // no further barriers: waves proceed independently

    const int lo = l & 31;
    const int hi = l >> 5;
    const int stride = gridDim.x * 8;
    int strip = blockIdx.x * 8 + wid;
    if (strip >= nstrips) return;

    auto zload = [&](int s_, short8* zz) {
        long long zr = (long long)s_ * 32 + lo;
        if (zr >= Mreal) zr = Mreal - 1;
        const unsigned short* zrow = Zin + zr * 128 + hi * 8;
#pragma unroll
        for (int s = 0; s < 8; ++s) zz[s] = *(const short8*)(zrow + s * 16);
    };

    short8 zc[8];
    zload(strip, zc);

    while (strip < nstrips) {
        const int nxt = strip + stride;
        float16v acc2[4] = {};
        short8 zn[8];

#pragma unroll
        for (int fp = 0; fp < NF / 2; ++fp) {
            if (fp == NF / 2 - 1) {
                if (nxt < nstrips) zload(nxt, zn);
            }
            const int f0 = 2 * fp, f1 = f0 + 1;
            float16v accA, accB;
#pragma unroll
            for (int q = 0; q < 4; ++q) {
                const float4 tA = *(const float4*)(blds + f0 * 32 + q * 8 + hi * 4);
                const float4 tB = *(const float4*)(blds + f1 * 32 + q * 8 + hi * 4);
                accA[4 * q + 0] = tA.x; accA[4 * q + 1] = tA.y;
                accA[4 * q + 2] = tA.z; accA[4 * q + 3] = tA.w;
                accB[4 * q + 0] = tB.x; accB[4 * q + 1] = tB.y;
                accB[4 * q + 2] = tB.z; accB[4 * q + 3] = tB.w;
            }
            const unsigned short* wa0 = wlds + ((long long)(f0 * 8) * 64 + l) * 8;
            const unsigned short* wa1 = wlds + ((long long)(f1 * 8) * 64 + l) * 8;
#pragma unroll
            for (int s = 0; s < 8; ++s) {
                short8 a0 = *(const short8*)(wa0 + s * 64 * 8);
                short8 a1 = *(const short8*)(wa1 + s * 64 * 8);
                accA = MFMA32(a0, zc[s], accA, 0, 0, 0);
                accB = MFMA32(a1, zc[s], accB, 0, 0, 0);
            }
#pragma unroll
            for (int r = 0; r < 16; ++r) {
                accA[r] = fmaxf(accA[r], 0.f);
                accB[r] = fmaxf(accB[r], 0.f);
            }
            short8 pa0, pa1, pa2, pa3;
            CVT_TO_PA2(accA, pa0, pa1);
            CVT_TO_PA2(accB, pa2, pa3);
            const unsigned short* wb = wlds + WAS + ((long long)(fp * 4) * 64 + l) * 8;
#pragma unroll
            for (int g = 0; g < 4; ++g) {
                const unsigned short* wbg = wb + (long long)g * NCH * 64 * 8;
                short8 b0 = *(const short8*)(wbg);
                short8 b1 = *(const short8*)(wbg + 64 * 8);
                short8 b2 = *(const short8*)(wbg + 2 * 64 * 8);
                short8 b3 = *(const short8*)(wbg + 3 * 64 * 8);
                acc2[g] = MFMA32(pa0, b0, acc2[g], 0, 0, 0);
                acc2[g] = MFMA32(pa1, b1, acc2[g], 0, 0, 0);
                acc2[g] = MFMA32(pa2, b2, acc2[g], 0, 0, 0);
                acc2[g] = MFMA32(pa3, b3, acc2[g], 0, 0, 0);
            }
        }

#pragma unroll
        for (int g = 0; g < 4; ++g) {
            const int col = g * 32 + lo;
            const float bv = blds[KMID + col];
#pragma unroll
            for (int r = 0; r < 16; ++r) {
                float v = acc2[g][r] + bv;
                if (RELU2) v = fmaxf(v, 0.f);
                const long long node = (long long)strip * 32 + (r & 3) + 8 * (r >> 2) + 4 * hi;
                if (node < Mreal) {
                    if (OUTF32) ((float*)outp)[node * 128 + col] = v;
                    else ((unsigned short*)outp)[node * 128 + col] = f2b(v);
                }
            }
        }

        strip = nxt;
        if (strip < nstrips) {
#pragma unroll
            for (int s = 0; s < 8; ++s) zc[s] = zn[s];
        }
    }
}

extern "C" void kernel_launch(void* const* d_in, const int* in_sizes, int n_in,
                              void* d_out, int out_size, void* d_ws, size_t ws_size,
                              hipStream_t stream) {
    const float* x    = (const float*)d_in[0];
    const int*   ei   = (const int*)d_in[1];
    const float* Wemb = (const float*)d_in[2];
    const float* eps1 = (const float*)d_in[3];
    const float* w1a  = (const float*)d_in[4];
    const float* b1a  = (const float*)d_in[5];
    const float* w1b  = (const float*)d_in[6];
    const float* b1b  = (const float*)d_in[7];
    const float* eps2 = (const float*)d_in[8];
    const float* w2a  = (const float*)d_in[9];
    const float* b2a  = (const float*)d_in[10];
    const float* w2b  = (const float*)d_in[11];
    const float* b2b  = (const float*)d_in[12];
    const float* eps3 = (const float*)d_in[13];
    const float* w3a  = (const float*)d_in[14];
    const float* b3a  = (const float*)d_in[15];
    const float* w3b  = (const float*)d_in[16];
    const float* b3b  = (const float*)d_in[17];

    const int N = in_sizes[0] / 64;   // 100000
    const int E = in_sizes[1] / 2;    // 1600000
    const int Mpad = ((N + 127) / 128) * 128;  // 100096
    const int NB = (N + BKT - 1) / BKT;   // 196
    const int G2 = 1024;
    const int PB = (E + G2 - 1) / G2;
    const int BH = NB * G2;

    char* ws = (char*)d_ws;
    size_t off = 0;
    auto alloc = [&](size_t bytes) -> void* {
        void* p = ws + off;
        off = (off + bytes + 255) & ~(size_t)255;
        return p;
    };
    unsigned short* Ha  = (unsigned short*)alloc((size_t)Mpad * 128 * 2);
    unsigned short* Hb2 = (unsigned short*)alloc((size_t)Mpad * 128 * 2);
    unsigned short* Zb  = (unsigned short*)alloc((size_t)Mpad * 128 * 2);
    unsigned short* pWe = (unsigned short*)alloc((size_t)64 * 128 * 2);
    unsigned short* p1a = (unsigned short*)alloc((size_t)128 * 128 * 2);
    unsigned short* p1b = (unsigned short*)alloc((size_t)128 * 128 * 2);
    unsigned short* p2a = (unsigned short*)alloc((size_t)128 * 256 * 2);
    unsigned short* p2b = (unsigned short*)alloc((size_t)256 * 128 * 2);
    unsigned short* p3a = (unsigned short*)alloc((size_t)128 * 256 * 2);
    unsigned short* p3b = (unsigned short*)alloc((size_t)256 * 128 * 2);
    int* offs = (int*)alloc((size_t)(N + 1) * 4);
    int* csr  = (int*)alloc((size_t)E * 4);
    unsigned int* staged = (unsigned int*)alloc((size_t)E * 4);
    int* bh   = (int*)alloc((size_t)BH * 4);
    int* bhs  = (int*)alloc((size_t)BH * 4);
    int* part = (int*)alloc(1024);
    int* boff = (int*)alloc(1024);

    // ---- CSR build (scan3 folded into scatter/csr_local) ----
    part_hist_kernel<<<G2, 256, 0, stream>>>(ei, bh, E, NB, PB);
    const int G1 = (BH + 1023) / 1024;   // 196
    scan1_kernel<<<G1, 1024, 0, stream>>>(bh, bhs, part, BH);
    scan2_kernel<<<1, 256, 0, stream>>>(part, boff, G1);
    part_scatter_kernel<<<G2, 256, 0, stream>>>(ei, bhs, boff, staged, E, NB, PB);
    csr_local_kernel<<<NB, 256, 0, stream>>>(staged, bhs, boff, offs, csr, N, E, NB, G2);

    // ---- fused weight packing ----
    {
        PWAll P;
        const PW descs[7] = {
            {Wemb, pWe, 64, 128}, {w1a, p1a, 128, 128}, {w1b, p1b, 128, 128},
            {w2a, p2a, 128, 256}, {w2b, p2b, 256, 128}, {w3a, p3a, 128, 256},
            {w3b, p3b, 256, 128}};
        int c = 0;
        for (int k = 0; k < 7; ++k) {
            P.d[k] = descs[k];
            P.cum[k] = c;
            c += (descs[k].KOUT / 32) * (descs[k].K / 16) * 64;
        }
        P.cum[7] = c;
        packall_kernel<<<(c + 255) / 256, 256, 0, stream>>>(P);
    }

    const int MMB = Mpad / 128;           // 782 tiles (embed)
    const int AGB = (N + 15) / 16;        // 16 nodes per block
    const int NSTRIP = (N + 31) / 32;     // 3125 strips (32 nodes each)

    // ---- embed: H = x @ W_embed (f32 read directly) ----
    mm_embed<<<MMB, 256, 0, stream>>>(x, pWe, Ha, N);

    // ---- layer 1: 128 -> 128(relu) -> 128  [65 KB LDS -> grid 512, 2 blk/CU] ----
    aggz_kernel<<<AGB, 256, 0, stream>>>(Ha, offs, csr, eps1, Zb, N);
    fused_mlp7<128, false, false><<<512, 512, 0, stream>>>(Zb, p1a, b1a, p1b, b1b, Hb2, N, NSTRIP);

    // ---- layer 2: 128 -> 256(relu) -> 128(relu) ----
    aggz_kernel<<<AGB, 256, 0, stream>>>(Hb2, offs, csr, eps2, Zb, N);
    fused_mlp7<256, true, false><<<256, 512, 0, stream>>>(Zb, p2a, b2a, p2b, b2b, Ha, N, NSTRIP);

    // ---- layer 3: 128 -> 256(relu) -> 128(relu), f32 out ----
    aggz_kernel<<<AGB, 256, 0, stream>>>(Ha, offs, csr, eps3, Zb, N);
    fused_mlp7<256, true, true><<<256, 512, 0, stream>>>(Zb, p3a, b3a, p3b, b3b, d_out, N, NSTRIP);
}